// Round 14
// baseline (613.824 us; speedup 1.0000x reference)
//
#include <hip/hip_runtime.h>
#include <hip/hip_bf16.h>

// Problem constants (B,T,NI,NH,NO fixed by the reference)
constexpr int kB  = 64;
constexpr int kT  = 100;
constexpr int kNI = 700;
constexpr int kNH = 512;
constexpr int kNO = 20;
constexpr float TAU   = 0.6f;
constexpr float TAU_O = 0.6f;
constexpr float THR   = 0.6f;
constexpr float LR    = 0.05f;

constexpr size_t BNH = (size_t)kB * kNH;   // 32768
constexpr size_t BNI = (size_t)kB * kNI;   // 44800
constexpr size_t BNO = (size_t)kB * kNO;   // 1280
constexpr int kK   = kT * kB;              // 6400 (grad-GEMM K; b-major: k = b*100+t)
constexpr int kKP  = 704;                  // padded K for xw GEMM

typedef __attribute__((ext_vector_type(8))) short short8;
typedef __attribute__((ext_vector_type(4))) float f32x4;

// ---------------- workspace layout (float offsets) ---------------------------
// XW+HSUR ([0, 6,553,600)) dead after k_forward -> 10 PGF + 10 PGR slices
// overlay them exactly. PGO gets fresh space at the end.
constexpr size_t O_XW   = 0;                                // [T, t*64+b, NH] 3,276,800
constexpr size_t O_HSUR = 3276800;                          // [T,B,NH] 3,276,800
constexpr size_t O_PGF  = 0;                                // 10 x [512][768] = 3,932,160
constexpr size_t O_PGR  = 3932160;                          // 10 x [512][512] = 2,621,440 (ends 6,553,600)
constexpr size_t O_ERR  = 6553600;                          // [T,B,NO] errf 128,000
constexpr size_t O_MTB  = 6681600;                          // bf16 [512][6400], b-major k
constexpr size_t O_TRB  = 8320000;                          // bf16 [512][6400], b-major k
constexpr size_t O_MSK  = 9958400;                          // u64 [T][B][8]
constexpr size_t O_TIB  = 10060800;                         // bf16 [700][6400] (ends 12,300,800)
constexpr size_t O_PGO  = 12300800;                         // 8 x [20][512] = 81,920
constexpr size_t O_CNT  = 12382720;                         // 64 int tile counters
constexpr size_t WS_FLOATS = 12382784;                      // ~49.5 MB

// d_out layout
constexpr size_t OUT_GF = (size_t)kB * kT * kNO;
constexpr size_t OUT_GR = OUT_GF + (size_t)kNH * kNI;
constexpr size_t OUT_GO = OUT_GR + (size_t)kNH * kNH;

// ---- XW = Xperm @ w_fc1^T : C[m=t*64+b, n<512], K=704 (fp32, exact) ---------
// 128x64 tiles (400 blocks). Block 0 also zeroes the k_grads tile counters
// (replaces the hipMemsetAsync launch; visible via kernel-boundary release).
__global__ __launch_bounds__(256) void k_xw2(const float* __restrict__ x,
                                             const float* __restrict__ wfc,
                                             float* __restrict__ ws) {
    int bx = blockIdx.x;                 // 400 = 50 mt x 8 nt
    int tid = threadIdx.x;
    if (bx == 0 && tid < 64) ((int*)(ws + O_CNT))[tid] = 0;
    float* XW = ws + O_XW;
    int mt = bx % 50, nt = bx / 50;
    int m0 = mt * 128, n0 = nt * 64;
    int tx = tid & 15, ty = tid >> 4;
    __shared__ float As[128][20];
    __shared__ float Bs[16][64];
    float acc[8][4] = {};
    int arow = tid >> 1, ahalf = tid & 1;
    int bb = (m0 + arow) & 63, tt = (m0 + arow) >> 6;
    const float* ap = x + ((size_t)bb * kT + tt) * kNI;
    int br = tid >> 2, bc4 = tid & 3;    // B stage: row n0+br, k-chunk bc4
    const float* wp = wfc + (size_t)(n0 + br) * kNI;
    for (int k0 = 0; k0 < kKP; k0 += 16) {
        #pragma unroll
        for (int u = 0; u < 2; u++) {
            int k = k0 + ahalf * 8 + u * 4;
            float4 v = (k + 3 < kNI) ? *(const float4*)(ap + k)
                                     : make_float4(0.f, 0.f, 0.f, 0.f);
            *(float4*)&As[arow][ahalf * 8 + u * 4] = v;
        }
        {
            int k = k0 + bc4 * 4;
            float4 v = (k + 3 < kNI) ? *(const float4*)(wp + k)
                                     : make_float4(0.f, 0.f, 0.f, 0.f);
            Bs[bc4 * 4 + 0][br] = v.x; Bs[bc4 * 4 + 1][br] = v.y;
            Bs[bc4 * 4 + 2][br] = v.z; Bs[bc4 * 4 + 3][br] = v.w;
        }
        __syncthreads();
        #pragma unroll
        for (int kk = 0; kk < 16; kk++) {
            float av[8];
            #pragma unroll
            for (int i = 0; i < 4; i++) {
                av[i]     = As[ty * 4 + i][kk];
                av[4 + i] = As[64 + ty * 4 + i][kk];
            }
            float4 b0 = *(const float4*)&Bs[kk][tx * 4];
            float bv[4] = {b0.x, b0.y, b0.z, b0.w};
            #pragma unroll
            for (int i = 0; i < 8; i++)
                #pragma unroll
                for (int j = 0; j < 4; j++) acc[i][j] += av[i] * bv[j];
        }
        __syncthreads();
    }
    #pragma unroll
    for (int i = 0; i < 8; i++) {
        int m = m0 + ((i < 4) ? (ty * 4 + i) : (64 + ty * 4 + i - 4));
        float* dst = XW + (size_t)m * kNH + n0;
        *(float4*)(dst + tx * 4) = make_float4(acc[i][0], acc[i][1], acc[i][2], acc[i][3]);
    }
}

// ---- fused forward + hidden tib cast ----------------------------------------
__global__ __launch_bounds__(832) void k_forward(float* __restrict__ ws,
                                                 const float* __restrict__ label,
                                                 const float* __restrict__ w_rec,
                                                 const float* __restrict__ w_out,
                                                 float* __restrict__ dout,
                                                 unsigned long long* __restrict__ gmask,
                                                 const float* __restrict__ x) {
    __shared__ float wout_ld[kNO * kNH];          // 40 KB
    __shared__ float partial[8][kNH];             // 16 KB
    __shared__ unsigned long long mh[kT * 8];     // 6.4 KB mask history
    __shared__ float errh[kT * kNO];              // 8 KB err/errf history

    int bxg = blockIdx.x, tid = threadIdx.x;
    if (bxg >= kB) {
        // tib[n=i][b*100+t] = bf16(tin scan of x), hidden under the forward
        int idx = (bxg - kB) * 832 + tid;
        if (idx < (int)BNI) {
            int b = idx / kNI, i = idx - b * kNI;
            const float* xp = x + (size_t)b * kT * kNI + i;
            unsigned short* tib = (unsigned short*)(ws + O_TIB);
            size_t rowoff = (size_t)i * kK + (size_t)b * 100;
            float v = 0.f;
            for (int tq = 0; tq < 25; tq++) {
                unsigned long long w8 = 0;
                #pragma unroll
                for (int u = 0; u < 4; u++) {
                    int t = tq * 4 + u;
                    v = TAU * v + xp[(size_t)t * kNI];
                    __hip_bfloat16 bv = __float2bfloat16(v);
                    w8 |= ((unsigned long long)*(unsigned short*)&bv) << (16 * u);
                }
                *(unsigned long long*)&tib[rowoff + tq * 4] = w8;
            }
        }
        return;
    }

    int b = bxg;
    int wave = tid >> 6, lane = tid & 63;
    const f32x4* wr4 = (const f32x4*)w_rec;
    for (int e = tid; e < kNO * kNH; e += 832) wout_ld[e] = w_out[e];
    float hm = 0.f, sp_prev = 0.f;
    float om_r[4] = {0.f, 0.f, 0.f, 0.f}, os_r[4] = {0.f, 0.f, 0.f, 0.f};
    int q = wave - 8;
    const int coff = lane * 2;
    __syncthreads();

    for (int t = 0; t < kT; t++) {
        float xw = 0.f;
        if (wave < 8) {
            xw = ws[O_XW + ((size_t)t * 64 + b) * kNH + tid];
            unsigned long long m = (t > 0) ? mh[(t - 1) * 8 + wave] : 0ull;
            const size_t base = (size_t)wave * 64;
            f32x4 s0 = {0.f, 0.f, 0.f, 0.f}, s1 = s0;
            while (m) {
                int j = __builtin_ctzll(m); m &= m - 1;
                const f32x4* r = wr4 + (base + j) * 128 + coff;
                s0 += r[0]; s1 += r[1];
            }
            *(f32x4*)&partial[wave][lane * 8]     = s0;
            *(f32x4*)&partial[wave][lane * 8 + 4] = s1;
        } else if (t > 0) {
            int to = t - 1;
            unsigned long long mk[8];
            #pragma unroll
            for (int k = 0; k < 8; k++) mk[k] = mh[to * 8 + k];
            #pragma unroll
            for (int r = 0; r < 4; r++) {
                int o = q * 4 + r;
                float p = 0.f;
                #pragma unroll
                for (int k = 0; k < 8; k++)
                    if ((mk[k] >> lane) & 1) p += wout_ld[o * kNH + 64 * k + lane];
                #pragma unroll
                for (int off = 32; off >= 1; off >>= 1) p += __shfl_xor(p, off);
                if (lane == 0) {
                    float om_n = TAU * om_r[r] * (1.f - os_r[r]) + p;
                    float os_n = (om_n >= THR) ? 1.f : 0.f;
                    om_r[r] = om_n; os_r[r] = os_n;
                    errh[to * kNO + o] = os_n - label[((size_t)b * kT + to) * kNO + o];
                    dout[((size_t)b * kT + to) * kNO + o] = os_n;
                }
            }
        }
        __syncthreads();
        if (tid < kNH) {
            float rec = ((partial[0][tid] + partial[1][tid]) + (partial[2][tid] + partial[3][tid]))
                      + ((partial[4][tid] + partial[5][tid]) + (partial[6][tid] + partial[7][tid]));
            hm = TAU * hm * (1.f - sp_prev) + (xw + rec);
            bool v = (hm >= THR);
            float sp = v ? 1.f : 0.f;
            sp_prev = sp;
            ws[O_HSUR + (size_t)t * BNH + (size_t)b * kNH + tid] =
                TAU * fmaxf(0.f, 1.f - fabsf(hm - THR) * (1.f / THR));
            unsigned long long bal = __ballot(v);
            if (lane == 0) {
                mh[t * 8 + wave] = bal;
                gmask[((size_t)t * 64 + b) * 8 + wave] = bal;
            }
        }
        __syncthreads();
    }
    // tail 1a: output layer for t = 99
    if (wave >= 8) {
        int to = kT - 1;
        unsigned long long mk[8];
        #pragma unroll
        for (int k = 0; k < 8; k++) mk[k] = mh[to * 8 + k];
        #pragma unroll
        for (int r = 0; r < 4; r++) {
            int o = q * 4 + r;
            float p = 0.f;
            #pragma unroll
            for (int k = 0; k < 8; k++)
                if ((mk[k] >> lane) & 1) p += wout_ld[o * kNH + 64 * k + lane];
            #pragma unroll
            for (int off = 32; off >= 1; off >>= 1) p += __shfl_xor(p, off);
            if (lane == 0) {
                float om_n = TAU * om_r[r] * (1.f - os_r[r]) + p;
                float os_n = (om_n >= THR) ? 1.f : 0.f;
                errh[to * kNO + o] = os_n - label[((size_t)b * kT + to) * kNO + o];
                dout[((size_t)b * kT + to) * kNO + o] = os_n;
            }
        }
    }
    // tail 1b (concurrent): trb[n][b*100+t] = bf16(trec) from mh
    if (tid < kNH) {
        unsigned short* trb = (unsigned short*)(ws + O_TRB);
        size_t rowoff = (size_t)tid * kK + (size_t)b * 100;
        int w = tid >> 6, bit = tid & 63;
        float v = 0.f, p = 0.f;
        for (int tq = 0; tq < 25; tq++) {
            unsigned long long w8 = 0;
            #pragma unroll
            for (int u = 0; u < 4; u++) {
                int t = tq * 4 + u;
                v = TAU * v + p;
                __hip_bfloat16 bv = __float2bfloat16(v);
                w8 |= ((unsigned long long)*(unsigned short*)&bv) << (16 * u);
                p = (float)((mh[t * 8 + w] >> bit) & 1ull);
            }
            *(unsigned long long*)&trb[rowoff + tq * 4] = w8;
        }
    }
    __syncthreads();
    // tail 2: reverse kappa scan (LDS) + errf -> global (t-major, for go)
    if (wave == 8 && lane < kNO) {
        float v = 0.f;
        for (int t = kT - 1; t >= 0; t--) {
            v = errh[t * kNO + lane] + TAU_O * v;
            errh[t * kNO + lane] = v;
            ws[O_ERR + (size_t)t * BNO + (size_t)b * kNO + lane] = v;
        }
    }
    __syncthreads();
    // tail 3: mtb[r][b*100+t] = bf16(LR*(errf@w_out)[r]*hsur[t][b][r])
    if (tid < kNH) {
        float wreg[kNO];
        #pragma unroll
        for (int o = 0; o < kNO; o++) wreg[o] = wout_ld[o * kNH + tid];
        unsigned short* mtb = (unsigned short*)(ws + O_MTB);
        size_t rowoff = (size_t)tid * kK + (size_t)b * 100;
        for (int tq = 0; tq < 25; tq++) {
            unsigned long long w8 = 0;
            #pragma unroll
            for (int u = 0; u < 4; u++) {
                int t = tq * 4 + u;
                float s = 0.f;
                #pragma unroll
                for (int o = 0; o < kNO; o++) s += errh[t * kNO + o] * wreg[o];
                float val = LR * s * ws[O_HSUR + (size_t)t * BNH + (size_t)b * kNH + tid];
                __hip_bfloat16 bv = __float2bfloat16(val);
                w8 |= ((unsigned long long)*(unsigned short*)&bv) << (16 * u);
            }
            *(unsigned long long*)&mtb[rowoff + tq * 4] = w8;
        }
    }
}

// ---- merged grads + self-reduction, splitK=10 -------------------------------
// Blocks 0..239 gf (10s x 4mt x 6nt), 240..399 gr (10s x 4mt x 4nt),
// 400..463 go (8s x 8nt). Last sibling of each tile group (agent-scope
// ACQ_REL counter) reduces ascending slices into dout (order = old
// k_reduce_all -> numerics preserved up to slice partitioning).
__global__ __launch_bounds__(256) void k_grads(float* __restrict__ ws,
                                               float* __restrict__ dout) {
    __shared__ unsigned short As[128 * 72];
    __shared__ unsigned short Bs[128 * 72];
    __shared__ int isLast;
    int bx = blockIdx.x, tid = threadIdx.x;
    int* cnt = (int*)(ws + O_CNT);

    if (bx < 400) {
        constexpr int KC = kK / 10, BK = 64, LDT = 72;   // KC = 640
        const unsigned short* A = (const unsigned short*)(ws + O_MTB);
        const unsigned short* B;
        float* Cpart;
        int Nrows, ldc, s, mt, nt, tileid;
        if (bx < 240) {
            s = bx % 10; int tmp = bx / 10;
            mt = tmp & 3; nt = tmp >> 2;                // 0..5
            B = (const unsigned short*)(ws + O_TIB);
            Cpart = ws + O_PGF; Nrows = kNI; ldc = 768;
            tileid = mt + 4 * nt;                       // 0..23
        } else {
            int v = bx - 240;
            s = v % 10; int tmp = v / 10;
            mt = tmp & 3; nt = tmp >> 2;                // 0..3
            B = (const unsigned short*)(ws + O_TRB);
            Cpart = ws + O_PGR; Nrows = kNH; ldc = kNH;
            tileid = 24 + mt + 4 * nt;                  // 24..39
        }
        int m0 = mt * 128, n0 = nt * 128, k0 = s * KC;
        int wave = tid >> 6, lane = tid & 63;
        int wm = wave & 1, wn = wave >> 1;
        f32x4 acc[4][4];
        #pragma unroll
        for (int i = 0; i < 4; i++)
            #pragma unroll
            for (int j = 0; j < 4; j++) acc[i][j] = (f32x4){0.f, 0.f, 0.f, 0.f};

        for (int kb = 0; kb < KC; kb += BK) {
            int kg = k0 + kb;
            #pragma unroll
            for (int p = 0; p < 4; p++) {
                int f = tid + p * 256;
                int row = f >> 3, seg = f & 7;
                *(short8*)&As[row * LDT + seg * 8] =
                    *(const short8*)&A[(size_t)(m0 + row) * kK + kg + seg * 8];
                short8 bv = {};
                if (n0 + row < Nrows)
                    bv = *(const short8*)&B[(size_t)(n0 + row) * kK + kg + seg * 8];
                *(short8*)&Bs[row * LDT + seg * 8] = bv;
            }
            __syncthreads();
            #pragma unroll
            for (int h = 0; h < 2; h++) {
                int kof = h * 32 + (lane >> 4) * 8;
                short8 af[4], bf[4];
                #pragma unroll
                for (int i = 0; i < 4; i++)
                    af[i] = *(short8*)&As[(wm * 64 + i * 16 + (lane & 15)) * LDT + kof];
                #pragma unroll
                for (int j = 0; j < 4; j++)
                    bf[j] = *(short8*)&Bs[(wn * 64 + j * 16 + (lane & 15)) * LDT + kof];
                #pragma unroll
                for (int i = 0; i < 4; i++)
                    #pragma unroll
                    for (int j = 0; j < 4; j++)
                        acc[i][j] = __builtin_amdgcn_mfma_f32_16x16x32_bf16(af[i], bf[j], acc[i][j], 0, 0, 0);
            }
            __syncthreads();
        }
        float* C = Cpart + (size_t)s * kNH * ldc;
        int rbase = (lane >> 4) * 4, col = lane & 15;
        #pragma unroll
        for (int i = 0; i < 4; i++)
            #pragma unroll
            for (int j = 0; j < 4; j++) {
                int n = n0 + wn * 64 + j * 16 + col;
                #pragma unroll
                for (int r = 0; r < 4; r++) {
                    int m = m0 + wm * 64 + i * 16 + rbase + r;
                    C[(size_t)m * ldc + n] = acc[i][j][r];
                }
            }
        // ---- last-sibling reduction (10 slices, ascending) ----
        __syncthreads();   // drain partial stores before release
        if (tid == 0)
            isLast = (__hip_atomic_fetch_add(&cnt[tileid], 1, __ATOMIC_ACQ_REL,
                                             __HIP_MEMORY_SCOPE_AGENT) == 9);
        __syncthreads();
        if (isLast) {
            if (bx < 240) {
                for (int e = tid; e < 128 * 128; e += 256) {
                    int m = m0 + (e >> 7), n = n0 + (e & 127);
                    if (n < kNI) {
                        float sv = 0.f;
                        size_t src = O_PGF + (size_t)m * 768 + n;
                        #pragma unroll
                        for (int k = 0; k < 10; k++) sv += ws[src + (size_t)k * kNH * 768];
                        dout[OUT_GF + (size_t)m * kNI + n] = sv;   // LR folded into mtb
                    }
                }
            } else {
                for (int e = tid; e < 128 * 128; e += 256) {
                    int m = m0 + (e >> 7), n = n0 + (e & 127);
                    float sv = 0.f;
                    size_t src = O_PGR + (size_t)m * kNH + n;
                    #pragma unroll
                    for (int k = 0; k < 10; k++) sv += ws[src + (size_t)k * kNH * kNH];
                    dout[OUT_GR + (size_t)m * kNH + n] = sv;
                }
            }
        }
    } else {
        // ---- go: fp32 TN GEMM, M=20, t-major k; B bits from gmask ----
        float* Asf = (float*)As;
        float* Bsf = (float*)Bs;
        const float* A = ws + O_ERR;
        const unsigned long long* gm = (const unsigned long long*)(ws + O_MSK);
        int v = bx - 400;
        int s = v & 7, nt = v >> 3;
        int n0 = nt * 64, k0 = s * 800;
        int w0 = n0 >> 6;
        int tx = tid & 15, ty = tid >> 4;
        float acc[4][4] = {};
        for (int kb = 0; kb < 800; kb += 16) {
            #pragma unroll
            for (int e = tid; e < 1024; e += 256) {
                int kk = e >> 6, c = e & 63;
                size_t gk = (size_t)(k0 + kb + kk);
                Asf[kk * 64 + c] = (c < kNO) ? A[gk * kNO + c] : 0.f;
                Bsf[kk * 64 + c] = (float)((gm[gk * 8 + w0] >> c) & 1ull);
            }
            __syncthreads();
            #pragma unroll
            for (int kk = 0; kk < 16; kk++) {
                float4 av = *(const float4*)&Asf[kk * 64 + ty * 4];
                float4 bv = *(const float4*)&Bsf[kk * 64 + tx * 4];
                float aa[4] = {av.x, av.y, av.z, av.w};
                float bb[4] = {bv.x, bv.y, bv.z, bv.w};
                #pragma unroll
                for (int a = 0; a < 4; a++)
                    #pragma unroll
                    for (int c = 0; c < 4; c++) acc[a][c] += aa[a] * bb[c];
            }
            __syncthreads();
        }
        float* Cs = ws + O_PGO + (size_t)s * kNO * kNH;
        #pragma unroll
        for (int a = 0; a < 4; a++) {
            int m = ty * 4 + a;
            if (m < kNO) {
                #pragma unroll
                for (int c = 0; c < 4; c++)
                    Cs[(size_t)m * kNH + n0 + tx * 4 + c] = acc[a][c];
            }
        }
        // ---- last-sibling reduction (8 slices) ----
        __syncthreads();
        if (tid == 0)
            isLast = (__hip_atomic_fetch_add(&cnt[40 + nt], 1, __ATOMIC_ACQ_REL,
                                             __HIP_MEMORY_SCOPE_AGENT) == 7);
        __syncthreads();
        if (isLast) {
            for (int e = tid; e < kNO * 64; e += 256) {
                int o = e >> 6, c = e & 63;
                float sv = 0.f;
                size_t src = O_PGO + (size_t)o * kNH + n0 + c;
                #pragma unroll
                for (int k = 0; k < 8; k++) sv += ws[src + (size_t)k * kNO * kNH];
                dout[OUT_GO + (size_t)o * kNH + n0 + c] = LR * sv;
            }
        }
    }
}

extern "C" void kernel_launch(void* const* d_in, const int* in_sizes, int n_in,
                              void* d_out, int out_size, void* d_ws, size_t ws_size,
                              hipStream_t stream) {
    (void)in_sizes; (void)n_in; (void)out_size;
    const float* x     = (const float*)d_in[0];
    const float* label = (const float*)d_in[1];
    const float* w_fc1 = (const float*)d_in[3];
    const float* w_rec = (const float*)d_in[4];
    const float* w_out = (const float*)d_in[5];
    float* out = (float*)d_out;
    float* ws  = (float*)d_ws;

    if (ws_size < WS_FLOATS * sizeof(float)) return;

    unsigned long long* gmask = (unsigned long long*)(ws + O_MSK);

    k_xw2<<<400, 256, 0, stream>>>(x, w_fc1, ws);   // also zeroes tile counters

    k_forward<<<kB + 54, 832, 0, stream>>>(ws, label, w_rec, w_out, out, gmask, x);

    k_grads<<<464, 256, 0, stream>>>(ws, out);      // gf + gr + go + reductions
}

// Round 15
// 608.491 us; speedup vs baseline: 1.0088x; 1.0088x over previous
//
#include <hip/hip_runtime.h>
#include <hip/hip_bf16.h>

// Problem constants (B,T,NI,NH,NO fixed by the reference)
constexpr int kB  = 64;
constexpr int kT  = 100;
constexpr int kNI = 700;
constexpr int kNH = 512;
constexpr int kNO = 20;
constexpr float TAU   = 0.6f;
constexpr float TAU_O = 0.6f;
constexpr float THR   = 0.6f;
constexpr float LR    = 0.05f;

constexpr size_t BNH = (size_t)kB * kNH;   // 32768
constexpr size_t BNI = (size_t)kB * kNI;   // 44800
constexpr size_t BNO = (size_t)kB * kNO;   // 1280
constexpr int kK   = kT * kB;              // 6400 (grad-GEMM K; b-major: k = b*100+t)
constexpr int kKP  = 704;                  // padded K for xw GEMM

typedef __attribute__((ext_vector_type(8))) short short8;
typedef __attribute__((ext_vector_type(4))) float f32x4;

// ---------------- workspace layout (float offsets) ---------------------------
// XW+HSUR dead after k_main -> PGF/PGR/PGO (splitK=4, R13 config) overlay XW.
constexpr size_t O_XW   = 0;                                // [T, t*64+b, NH] 3,276,800
constexpr size_t O_PGF  = 0;                                // 4 x [512][768] = 1,572,864
constexpr size_t O_PGR  = 1572864;                          // 4 x [512][512] = 1,048,576
constexpr size_t O_PGO  = 2621440;                          // 8 x [20][512]  = 81,920
constexpr size_t O_HSUR = 3276800;                          // [T,B,NH] 3,276,800
constexpr size_t O_ERR  = 6553600;                          // [T,B,NO] errf 128,000
constexpr size_t O_MTB  = 6681600;                          // bf16 [512][6400], b-major k
constexpr size_t O_TRB  = 8320000;                          // bf16 [512][6400], b-major k
constexpr size_t O_MSK  = 9958400;                          // u64 [T][B][8]
constexpr size_t O_TIB  = 10060800;                         // bf16 [700][6400] (ends 12,300,800)
constexpr size_t O_CNT  = 12300800;                         // 128 int counters:
                                                            //   [0..49] xw per-mt flags
                                                            //   [50..89] gf/gr tiles, [90..97] go
constexpr size_t WS_FLOATS = 12300928;                      // ~49.2 MB

// d_out layout
constexpr size_t OUT_GF = (size_t)kB * kT * kNO;
constexpr size_t OUT_GR = OUT_GF + (size_t)kNH * kNI;
constexpr size_t OUT_GO = OUT_GR + (size_t)kNH * kNH;

// ---- fused: xw GEMM (blocks 0..399) + forward (400..463) + tib cast (464+) --
// xw: 128x64 tiles, mt-major (mt=bx>>3) so early row-groups finish first; each
// tile bumps cnt[mt] with agent-scope release. Forward polls cnt[(t+1)>>1]
// (relaxed; safe: first-touch + clean-L2-at-launch + producer release) one
// step ahead, so pipelining adds no extra barriers. XW values bit-identical
// to the standalone kernel.
__global__ __launch_bounds__(832) void k_main(float* __restrict__ ws,
                                              const float* __restrict__ label,
                                              const float* __restrict__ w_rec,
                                              const float* __restrict__ w_out,
                                              float* __restrict__ dout,
                                              unsigned long long* __restrict__ gmask,
                                              const float* __restrict__ x,
                                              const float* __restrict__ wfc) {
    __shared__ __align__(16) char smem[71744];
    int bx = blockIdx.x, tid = threadIdx.x;
    int* cnt = (int*)(ws + O_CNT);

    if (bx < 400) {
        // ---------------- xw producer ----------------
        float* As = (float*)smem;             // [128][20]
        float* Bs = (float*)(smem + 40960);   // [16][64]
        int mt = bx >> 3, nt = bx & 7;
        int m0 = mt * 128, n0 = nt * 64;
        float acc[8][4] = {};
        int tx = tid & 15, ty = (tid >> 4) & 15;
        int arow = (tid >> 1) & 127, ahalf = tid & 1;
        int bb = (m0 + arow) & 63, tt = (m0 + arow) >> 6;
        const float* ap = x + ((size_t)bb * kT + tt) * kNI;
        int br = (tid >> 2) & 63, bc4 = tid & 3;
        const float* wp = wfc + (size_t)(n0 + br) * kNI;
        for (int k0 = 0; k0 < kKP; k0 += 16) {
            if (tid < 256) {
                #pragma unroll
                for (int u = 0; u < 2; u++) {
                    int k = k0 + ahalf * 8 + u * 4;
                    float4 v = (k + 3 < kNI) ? *(const float4*)(ap + k)
                                             : make_float4(0.f, 0.f, 0.f, 0.f);
                    *(float4*)&As[arow * 20 + ahalf * 8 + u * 4] = v;
                }
                int k = k0 + bc4 * 4;
                float4 v = (k + 3 < kNI) ? *(const float4*)(wp + k)
                                         : make_float4(0.f, 0.f, 0.f, 0.f);
                Bs[(bc4 * 4 + 0) * 64 + br] = v.x; Bs[(bc4 * 4 + 1) * 64 + br] = v.y;
                Bs[(bc4 * 4 + 2) * 64 + br] = v.z; Bs[(bc4 * 4 + 3) * 64 + br] = v.w;
            }
            __syncthreads();
            if (tid < 256) {
                #pragma unroll
                for (int kk = 0; kk < 16; kk++) {
                    float av[8];
                    #pragma unroll
                    for (int i = 0; i < 4; i++) {
                        av[i]     = As[(ty * 4 + i) * 20 + kk];
                        av[4 + i] = As[(64 + ty * 4 + i) * 20 + kk];
                    }
                    float4 b0 = *(const float4*)&Bs[kk * 64 + tx * 4];
                    float bv[4] = {b0.x, b0.y, b0.z, b0.w};
                    #pragma unroll
                    for (int i = 0; i < 8; i++)
                        #pragma unroll
                        for (int j = 0; j < 4; j++) acc[i][j] += av[i] * bv[j];
                }
            }
            __syncthreads();
        }
        if (tid < 256) {
            #pragma unroll
            for (int i = 0; i < 8; i++) {
                int m = m0 + ((i < 4) ? (ty * 4 + i) : (64 + ty * 4 + i - 4));
                float* dst = ws + O_XW + (size_t)m * kNH + n0;
                *(float4*)(dst + tx * 4) = make_float4(acc[i][0], acc[i][1], acc[i][2], acc[i][3]);
            }
        }
        __syncthreads();   // drains vmcnt: tile stores complete before release
        if (tid == 0)
            __hip_atomic_fetch_add(&cnt[mt], 1, __ATOMIC_ACQ_REL, __HIP_MEMORY_SCOPE_AGENT);
        return;
    }

    if (bx >= 464) {
        // ---------------- tib cast (hidden) ----------------
        int idx = (bx - 464) * 832 + tid;
        if (idx < (int)BNI) {
            int b = idx / kNI, i = idx - b * kNI;
            const float* xp = x + (size_t)b * kT * kNI + i;
            unsigned short* tib = (unsigned short*)(ws + O_TIB);
            size_t rowoff = (size_t)i * kK + (size_t)b * 100;
            float v = 0.f;
            for (int tq = 0; tq < 25; tq++) {
                unsigned long long w8 = 0;
                #pragma unroll
                for (int u = 0; u < 4; u++) {
                    int t = tq * 4 + u;
                    v = TAU * v + xp[(size_t)t * kNI];
                    __hip_bfloat16 bv = __float2bfloat16(v);
                    w8 |= ((unsigned long long)*(unsigned short*)&bv) << (16 * u);
                }
                *(unsigned long long*)&tib[rowoff + tq * 4] = w8;
            }
        }
        return;
    }

    // ---------------- forward ----------------
    float* wout_ld = (float*)smem;                         // [20*512]
    float* partial = (float*)(smem + 40960);               // [8*512]
    unsigned long long* mh = (unsigned long long*)(smem + 57344);  // [100*8]
    float* errh = (float*)(smem + 63744);                  // [100*20]

    int b = bx - 400;
    int wave = tid >> 6, lane = tid & 63;
    const f32x4* wr4 = (const f32x4*)w_rec;
    for (int e = tid; e < kNO * kNH; e += 832) wout_ld[e] = w_out[e];
    float hm = 0.f, sp_prev = 0.f;
    float om_r[4] = {0.f, 0.f, 0.f, 0.f}, os_r[4] = {0.f, 0.f, 0.f, 0.f};
    int q = wave - 8;
    const int coff = lane * 2;
    int mtw = 0;
    if (tid == 0) {
        while (__hip_atomic_load(&cnt[0], __ATOMIC_RELAXED, __HIP_MEMORY_SCOPE_AGENT) < 8)
            __builtin_amdgcn_s_sleep(8);
    }
    __syncthreads();

    for (int t = 0; t < kT; t++) {
        float xw = 0.f;
        if (wave < 8) {
            xw = ws[O_XW + ((size_t)t * 64 + b) * kNH + tid];
            unsigned long long m = (t > 0) ? mh[(t - 1) * 8 + wave] : 0ull;
            const size_t base = (size_t)wave * 64;
            f32x4 s0 = {0.f, 0.f, 0.f, 0.f}, s1 = s0;
            while (m) {
                int j = __builtin_ctzll(m); m &= m - 1;
                const f32x4* r = wr4 + (base + j) * 128 + coff;
                s0 += r[0]; s1 += r[1];
            }
            *(f32x4*)&partial[wave * kNH + lane * 8]     = s0;
            *(f32x4*)&partial[wave * kNH + lane * 8 + 4] = s1;
        } else if (t > 0) {
            int to = t - 1;
            unsigned long long mk[8];
            #pragma unroll
            for (int k = 0; k < 8; k++) mk[k] = mh[to * 8 + k];
            #pragma unroll
            for (int r = 0; r < 4; r++) {
                int o = q * 4 + r;
                float p = 0.f;
                #pragma unroll
                for (int k = 0; k < 8; k++)
                    if ((mk[k] >> lane) & 1) p += wout_ld[o * kNH + 64 * k + lane];
                #pragma unroll
                for (int off = 32; off >= 1; off >>= 1) p += __shfl_xor(p, off);
                if (lane == 0) {
                    float om_n = TAU * om_r[r] * (1.f - os_r[r]) + p;
                    float os_n = (om_n >= THR) ? 1.f : 0.f;
                    om_r[r] = om_n; os_r[r] = os_n;
                    errh[to * kNO + o] = os_n - label[((size_t)b * kT + to) * kNO + o];
                    dout[((size_t)b * kT + to) * kNO + o] = os_n;
                }
            }
        }
        __syncthreads();
        if (tid < kNH) {
            float rec = ((partial[0 * kNH + tid] + partial[1 * kNH + tid]) +
                         (partial[2 * kNH + tid] + partial[3 * kNH + tid])) +
                        ((partial[4 * kNH + tid] + partial[5 * kNH + tid]) +
                         (partial[6 * kNH + tid] + partial[7 * kNH + tid]));
            hm = TAU * hm * (1.f - sp_prev) + (xw + rec);
            bool v = (hm >= THR);
            float sp = v ? 1.f : 0.f;
            sp_prev = sp;
            ws[O_HSUR + (size_t)t * BNH + (size_t)b * kNH + tid] =
                TAU * fmaxf(0.f, 1.f - fabsf(hm - THR) * (1.f / THR));
            unsigned long long bal = __ballot(v);
            if (lane == 0) {
                mh[t * 8 + wave] = bal;
                gmask[((size_t)t * 64 + b) * 8 + wave] = bal;
            }
        }
        // poll one step ahead for the next XW row-group (no extra barrier)
        if (tid == 0) {
            int nmt = (t + 1) >> 1;
            if (nmt > mtw && nmt < 50) {
                while (__hip_atomic_load(&cnt[nmt], __ATOMIC_RELAXED, __HIP_MEMORY_SCOPE_AGENT) < 8)
                    __builtin_amdgcn_s_sleep(8);
                mtw = nmt;
            }
        }
        __syncthreads();
    }
    // tail 1a: output layer for t = 99
    if (wave >= 8) {
        int to = kT - 1;
        unsigned long long mk[8];
        #pragma unroll
        for (int k = 0; k < 8; k++) mk[k] = mh[to * 8 + k];
        #pragma unroll
        for (int r = 0; r < 4; r++) {
            int o = q * 4 + r;
            float p = 0.f;
            #pragma unroll
            for (int k = 0; k < 8; k++)
                if ((mk[k] >> lane) & 1) p += wout_ld[o * kNH + 64 * k + lane];
            #pragma unroll
            for (int off = 32; off >= 1; off >>= 1) p += __shfl_xor(p, off);
            if (lane == 0) {
                float om_n = TAU * om_r[r] * (1.f - os_r[r]) + p;
                float os_n = (om_n >= THR) ? 1.f : 0.f;
                errh[to * kNO + o] = os_n - label[((size_t)b * kT + to) * kNO + o];
                dout[((size_t)b * kT + to) * kNO + o] = os_n;
            }
        }
    }
    // tail 1b (concurrent): trb[n][b*100+t] = bf16(trec) from mh
    if (tid < kNH) {
        unsigned short* trb = (unsigned short*)(ws + O_TRB);
        size_t rowoff = (size_t)tid * kK + (size_t)b * 100;
        int w = tid >> 6, bit = tid & 63;
        float v = 0.f, p = 0.f;
        for (int tq = 0; tq < 25; tq++) {
            unsigned long long w8 = 0;
            #pragma unroll
            for (int u = 0; u < 4; u++) {
                int t = tq * 4 + u;
                v = TAU * v + p;
                __hip_bfloat16 bv = __float2bfloat16(v);
                w8 |= ((unsigned long long)*(unsigned short*)&bv) << (16 * u);
                p = (float)((mh[t * 8 + w] >> bit) & 1ull);
            }
            *(unsigned long long*)&trb[rowoff + tq * 4] = w8;
        }
    }
    __syncthreads();
    // tail 2: reverse kappa scan (LDS) + errf -> global (t-major, for go)
    if (wave == 8 && lane < kNO) {
        float v = 0.f;
        for (int t = kT - 1; t >= 0; t--) {
            v = errh[t * kNO + lane] + TAU_O * v;
            errh[t * kNO + lane] = v;
            ws[O_ERR + (size_t)t * BNO + (size_t)b * kNO + lane] = v;
        }
    }
    __syncthreads();
    // tail 3: mtb[r][b*100+t] = bf16(LR*(errf@w_out)[r]*hsur[t][b][r])
    if (tid < kNH) {
        float wreg[kNO];
        #pragma unroll
        for (int o = 0; o < kNO; o++) wreg[o] = wout_ld[o * kNH + tid];
        unsigned short* mtb = (unsigned short*)(ws + O_MTB);
        size_t rowoff = (size_t)tid * kK + (size_t)b * 100;
        for (int tq = 0; tq < 25; tq++) {
            unsigned long long w8 = 0;
            #pragma unroll
            for (int u = 0; u < 4; u++) {
                int t = tq * 4 + u;
                float s = 0.f;
                #pragma unroll
                for (int o = 0; o < kNO; o++) s += errh[t * kNO + o] * wreg[o];
                float val = LR * s * ws[O_HSUR + (size_t)t * BNH + (size_t)b * kNH + tid];
                __hip_bfloat16 bv = __float2bfloat16(val);
                w8 |= ((unsigned long long)*(unsigned short*)&bv) << (16 * u);
            }
            *(unsigned long long*)&mtb[rowoff + tq * 4] = w8;
        }
    }
}

// ---- merged grads + self-reduction, splitK=4 (R13 config) -------------------
__global__ __launch_bounds__(256) void k_grads(float* __restrict__ ws,
                                               float* __restrict__ dout) {
    __shared__ unsigned short As[128 * 72];
    __shared__ unsigned short Bs[128 * 72];
    __shared__ int isLast;
    int bx = blockIdx.x, tid = threadIdx.x;
    int* cnt = (int*)(ws + O_CNT);

    if (bx < 160) {
        constexpr int KC = kK / 4, BK = 64, LDT = 72;
        const unsigned short* A = (const unsigned short*)(ws + O_MTB);
        const unsigned short* B;
        float* Cpart;
        int Nrows, ldc, s, mt, nt, tileid;
        if (bx < 96) {
            s = bx & 3; mt = (bx >> 2) & 3; nt = bx >> 4;
            B = (const unsigned short*)(ws + O_TIB);
            Cpart = ws + O_PGF; Nrows = kNI; ldc = 768;
            tileid = mt + 4 * nt;                       // 0..23
        } else {
            int v = bx - 96;
            s = v & 3; mt = (v >> 2) & 3; nt = v >> 4;
            B = (const unsigned short*)(ws + O_TRB);
            Cpart = ws + O_PGR; Nrows = kNH; ldc = kNH;
            tileid = 24 + mt + 4 * nt;                  // 24..39
        }
        int m0 = mt * 128, n0 = nt * 128, k0 = s * KC;
        int wave = tid >> 6, lane = tid & 63;
        int wm = wave & 1, wn = wave >> 1;
        f32x4 acc[4][4];
        #pragma unroll
        for (int i = 0; i < 4; i++)
            #pragma unroll
            for (int j = 0; j < 4; j++) acc[i][j] = (f32x4){0.f, 0.f, 0.f, 0.f};

        for (int kb = 0; kb < KC; kb += BK) {
            int kg = k0 + kb;
            #pragma unroll
            for (int p = 0; p < 4; p++) {
                int f = tid + p * 256;
                int row = f >> 3, seg = f & 7;
                *(short8*)&As[row * LDT + seg * 8] =
                    *(const short8*)&A[(size_t)(m0 + row) * kK + kg + seg * 8];
                short8 bv = {};
                if (n0 + row < Nrows)
                    bv = *(const short8*)&B[(size_t)(n0 + row) * kK + kg + seg * 8];
                *(short8*)&Bs[row * LDT + seg * 8] = bv;
            }
            __syncthreads();
            #pragma unroll
            for (int h = 0; h < 2; h++) {
                int kof = h * 32 + (lane >> 4) * 8;
                short8 af[4], bf[4];
                #pragma unroll
                for (int i = 0; i < 4; i++)
                    af[i] = *(short8*)&As[(wm * 64 + i * 16 + (lane & 15)) * LDT + kof];
                #pragma unroll
                for (int j = 0; j < 4; j++)
                    bf[j] = *(short8*)&Bs[(wn * 64 + j * 16 + (lane & 15)) * LDT + kof];
                #pragma unroll
                for (int i = 0; i < 4; i++)
                    #pragma unroll
                    for (int j = 0; j < 4; j++)
                        acc[i][j] = __builtin_amdgcn_mfma_f32_16x16x32_bf16(af[i], bf[j], acc[i][j], 0, 0, 0);
            }
            __syncthreads();
        }
        float* C = Cpart + (size_t)s * kNH * ldc;
        int rbase = (lane >> 4) * 4, col = lane & 15;
        #pragma unroll
        for (int i = 0; i < 4; i++)
            #pragma unroll
            for (int j = 0; j < 4; j++) {
                int n = n0 + wn * 64 + j * 16 + col;
                #pragma unroll
                for (int r = 0; r < 4; r++) {
                    int m = m0 + wm * 64 + i * 16 + rbase + r;
                    C[(size_t)m * ldc + n] = acc[i][j][r];
                }
            }
        // last-sibling reduction (4 slices, ascending)
        __syncthreads();
        if (tid == 0)
            isLast = (__hip_atomic_fetch_add(&cnt[50 + tileid], 1, __ATOMIC_ACQ_REL,
                                             __HIP_MEMORY_SCOPE_AGENT) == 3);
        __syncthreads();
        if (isLast) {
            if (bx < 96) {
                for (int e = tid; e < 128 * 128; e += 256) {
                    int m = m0 + (e >> 7), n = n0 + (e & 127);
                    if (n < kNI) {
                        float sv = 0.f;
                        size_t src = O_PGF + (size_t)m * 768 + n;
                        #pragma unroll
                        for (int k = 0; k < 4; k++) sv += ws[src + (size_t)k * kNH * 768];
                        dout[OUT_GF + (size_t)m * kNI + n] = sv;   // LR folded into mtb
                    }
                }
            } else {
                for (int e = tid; e < 128 * 128; e += 256) {
                    int m = m0 + (e >> 7), n = n0 + (e & 127);
                    float sv = 0.f;
                    size_t src = O_PGR + (size_t)m * kNH + n;
                    #pragma unroll
                    for (int k = 0; k < 4; k++) sv += ws[src + (size_t)k * kNH * kNH];
                    dout[OUT_GR + (size_t)m * kNH + n] = sv;
                }
            }
        }
    } else {
        // go: fp32 TN GEMM, M=20, t-major k; B bits from gmask
        float* Asf = (float*)As;
        float* Bsf = (float*)Bs;
        const float* A = ws + O_ERR;
        const unsigned long long* gm = (const unsigned long long*)(ws + O_MSK);
        int v = bx - 160;
        int s = v & 7, nt = v >> 3;
        int n0 = nt * 64, k0 = s * 800;
        int w0 = n0 >> 6;
        int tx = tid & 15, ty = tid >> 4;
        float acc[4][4] = {};
        for (int kb = 0; kb < 800; kb += 16) {
            #pragma unroll
            for (int e = tid; e < 1024; e += 256) {
                int kk = e >> 6, c = e & 63;
                size_t gk = (size_t)(k0 + kb + kk);
                Asf[kk * 64 + c] = (c < kNO) ? A[gk * kNO + c] : 0.f;
                Bsf[kk * 64 + c] = (float)((gm[gk * 8 + w0] >> c) & 1ull);
            }
            __syncthreads();
            #pragma unroll
            for (int kk = 0; kk < 16; kk++) {
                float4 av = *(const float4*)&Asf[kk * 64 + ty * 4];
                float4 bv = *(const float4*)&Bsf[kk * 64 + tx * 4];
                float aa[4] = {av.x, av.y, av.z, av.w};
                float bb[4] = {bv.x, bv.y, bv.z, bv.w};
                #pragma unroll
                for (int a = 0; a < 4; a++)
                    #pragma unroll
                    for (int c = 0; c < 4; c++) acc[a][c] += aa[a] * bb[c];
            }
            __syncthreads();
        }
        float* Cs = ws + O_PGO + (size_t)s * kNO * kNH;
        #pragma unroll
        for (int a = 0; a < 4; a++) {
            int m = ty * 4 + a;
            if (m < kNO) {
                #pragma unroll
                for (int c = 0; c < 4; c++)
                    Cs[(size_t)m * kNH + n0 + tx * 4 + c] = acc[a][c];
            }
        }
        __syncthreads();
        if (tid == 0)
            isLast = (__hip_atomic_fetch_add(&cnt[90 + nt], 1, __ATOMIC_ACQ_REL,
                                             __HIP_MEMORY_SCOPE_AGENT) == 7);
        __syncthreads();
        if (isLast) {
            for (int e = tid; e < kNO * 64; e += 256) {
                int o = e >> 6, c = e & 63;
                float sv = 0.f;
                size_t src = O_PGO + (size_t)o * kNH + n0 + c;
                #pragma unroll
                for (int k = 0; k < 8; k++) sv += ws[src + (size_t)k * kNO * kNH];
                dout[OUT_GO + (size_t)o * kNH + n0 + c] = LR * sv;
            }
        }
    }
}

extern "C" void kernel_launch(void* const* d_in, const int* in_sizes, int n_in,
                              void* d_out, int out_size, void* d_ws, size_t ws_size,
                              hipStream_t stream) {
    (void)in_sizes; (void)n_in; (void)out_size;
    const float* x     = (const float*)d_in[0];
    const float* label = (const float*)d_in[1];
    const float* w_fc1 = (const float*)d_in[3];
    const float* w_rec = (const float*)d_in[4];
    const float* w_out = (const float*)d_in[5];
    float* out = (float*)d_out;
    float* ws  = (float*)d_ws;

    if (ws_size < WS_FLOATS * sizeof(float)) return;

    unsigned long long* gmask = (unsigned long long*)(ws + O_MSK);

    hipMemsetAsync(ws + O_CNT, 0, 128 * sizeof(int), stream);

    k_main<<<518, 832, 0, stream>>>(ws, label, w_rec, w_out, out, gmask, x, w_fc1);

    k_grads<<<224, 256, 0, stream>>>(ws, out);
}